// Round 4
// baseline (787.721 us; speedup 1.0000x reference)
//
#include <hip/hip_runtime.h>

#define B 32
#define LQ 32
#define DLEN 4096
#define P 16
#define D 2048
#define H 2048
#define NC 32   // doc chunks per batch (grid.x of psum)
#define HC 64   // h-rows per v_kernel block
#define HB 4    // W-rows per qenc block

// ws layout (floats): p_sum[B*P*D] | v[B*D] | qb[B] | q_rep[B*D] | q_enc[B*H]
#define ZERO_N (B * P * D + B * D + B)

// ---------------------------------------------------------------------------
// K0: zero p_sum, v, qb (contiguous prefix of ws).
// ---------------------------------------------------------------------------
__global__ __launch_bounds__(256) void zero_kernel(float* __restrict__ ws) {
  const int i = blockIdx.x * 256 + threadIdx.x;
  if (i < ZERO_N) ws[i] = 0.f;
}

// ---------------------------------------------------------------------------
// K1 (dominant): per-passage embedding sums, token-balanced.
// grid = (NC, B). Block owns a contiguous token chunk of batch b; the chunk
// spans few passage segments (tokens sorted by passage). For each segment:
// 256 threads cooperatively stream rows (thread owns float4 cols tid and
// tid+256 -> 8KB/row coalesced), accumulate in registers, then 8 atomics
// per thread into p_sum[b*P+p]. No shuffles in the hot loop.
// ---------------------------------------------------------------------------
__global__ __launch_bounds__(256) void psum_kernel(
    const int* __restrict__ docs, const int* __restrict__ plen,
    const float* __restrict__ emb, float* __restrict__ p_sum) {
  const int b = blockIdx.y;
  __shared__ int cum[P];
  __shared__ int stok[128];

  if (threadIdx.x == 0) {
    int s = 0;
#pragma unroll
    for (int i = 0; i < P; ++i) { s += plen[b * P + i]; cum[i] = s; }
  }
  __syncthreads();

  const int tot = cum[P - 1];
  const int per = (tot + NC - 1) / NC;              // <= 128
  const int t0  = blockIdx.x * per;
  const int t1  = (t0 + per < tot) ? (t0 + per) : tot;
  if (t0 >= t1) return;

  for (int i = threadIdx.x; i < t1 - t0; i += 256)
    stok[i] = docs[b * DLEN + t0 + i];
  __syncthreads();

  // first passage containing t0
  int p = 0;
#pragma unroll
  for (int j = 0; j < P; ++j) p += (cum[j] <= t0) ? 1 : 0;

  const int tid = threadIdx.x;
  int segStart = t0;
  while (segStart < t1) {
    const int segEnd = (cum[p] < t1) ? cum[p] : t1;
    float4 a0 = make_float4(0.f, 0.f, 0.f, 0.f);
    float4 a1 = make_float4(0.f, 0.f, 0.f, 0.f);
#pragma unroll 2
    for (int t = segStart; t < segEnd; ++t) {
      const float4* r = (const float4*)(emb + (size_t)stok[t - t0] * D);
      const float4 x = r[tid];
      const float4 y = r[tid + 256];
      a0.x += x.x; a0.y += x.y; a0.z += x.z; a0.w += x.w;
      a1.x += y.x; a1.y += y.y; a1.z += y.z; a1.w += y.w;
    }
    float* dst = p_sum + (size_t)(b * P + p) * D;
    atomicAdd(&dst[tid * 4 + 0], a0.x);
    atomicAdd(&dst[tid * 4 + 1], a0.y);
    atomicAdd(&dst[tid * 4 + 2], a0.z);
    atomicAdd(&dst[tid * 4 + 3], a0.w);
    atomicAdd(&dst[1024 + tid * 4 + 0], a1.x);
    atomicAdd(&dst[1024 + tid * 4 + 1], a1.y);
    atomicAdd(&dst[1024 + tid * 4 + 2], a1.z);
    atomicAdd(&dst[1024 + tid * 4 + 3], a1.w);
    segStart = segEnd;
    ++p;
  }
}

// ---------------------------------------------------------------------------
// K2: q_rep[b][:] = masked mean of query token embeddings. 32 blocks.
// ---------------------------------------------------------------------------
__global__ __launch_bounds__(256) void qrep_kernel(
    const int* __restrict__ queries, const int* __restrict__ qlen,
    const float* __restrict__ emb, float* __restrict__ q_rep) {
  __shared__ int stok[LQ];
  const int b   = blockIdx.x;
  const int len = qlen[b];
  if (threadIdx.x < len) stok[threadIdx.x] = queries[b * LQ + threadIdx.x];
  __syncthreads();

  float4 a0 = make_float4(0.f, 0.f, 0.f, 0.f);
  float4 a1 = make_float4(0.f, 0.f, 0.f, 0.f);
  for (int t = 0; t < len; ++t) {
    const float4* r = (const float4*)(emb + (size_t)stok[t] * D);
    const float4 x = r[threadIdx.x];
    const float4 y = r[threadIdx.x + 256];
    a0.x += x.x; a0.y += x.y; a0.z += x.z; a0.w += x.w;
    a1.x += y.x; a1.y += y.y; a1.z += y.z; a1.w += y.w;
  }
  const float inv = 1.0f / (float)(len > 0 ? len : 1);
  float4* o = (float4*)(q_rep + (size_t)b * D);
  o[threadIdx.x]       = make_float4(a0.x*inv, a0.y*inv, a0.z*inv, a0.w*inv);
  o[threadIdx.x + 256] = make_float4(a1.x*inv, a1.y*inv, a1.z*inv, a1.w*inv);
}

// ---------------------------------------------------------------------------
// K3: q_enc[b][h] = dot(q_rep[b], W[h]) + bias[h]; also accumulates
// qb[b] += sum_r q_enc[b][h0+r] * bias[h0+r] via one atomic per (block,b).
// grid = H/HB blocks; HB W-rows staged in LDS; 4 waves own disjoint b's.
// ---------------------------------------------------------------------------
__global__ __launch_bounds__(256) void qenc_kernel(
    const float* __restrict__ q_rep, const float* __restrict__ W,
    const float* __restrict__ bias, float* __restrict__ q_enc,
    float* __restrict__ qb) {
  const int h0 = blockIdx.x * HB;
  __shared__ float4 wsh[HB][D / 4];
  for (int i = threadIdx.x; i < HB * (D / 4); i += 256) {
    const int r = i / (D / 4), c = i % (D / 4);
    wsh[r][c] = ((const float4*)(W + (size_t)(h0 + r) * D))[c];
  }
  __syncthreads();

  const int lane = threadIdx.x & 63, wid = threadIdx.x >> 6;
  for (int b = wid; b < B; b += 4) {
    const float4* q4 = (const float4*)(q_rep + (size_t)b * D);
    float s[HB] = {0.f, 0.f, 0.f, 0.f};
#pragma unroll
    for (int j = 0; j < 8; ++j) {
      const float4 q = q4[j * 64 + lane];
#pragma unroll
      for (int r = 0; r < HB; ++r) {
        const float4 w = wsh[r][j * 64 + lane];
        s[r] += w.x * q.x + w.y * q.y + w.z * q.z + w.w * q.w;
      }
    }
    float qbp = 0.f;
#pragma unroll
    for (int r = 0; r < HB; ++r) {
      float t = s[r];
#pragma unroll
      for (int off = 32; off; off >>= 1) t += __shfl_down(t, off, 64);
      if (lane == 0) {
        const float bh  = bias[h0 + r];
        const float val = t + bh;
        q_enc[b * H + h0 + r] = val;
        qbp += val * bh;
      }
    }
    if (lane == 0) atomicAdd(&qb[b], qbp);
  }
}

// ---------------------------------------------------------------------------
// K4: v[b][d] += sum_{h in chunk} q_enc[b][h] * W[h][d].
// grid = (D/256, H/HC) = 256 blocks; atomic conflict degree H/HC = 32.
// ---------------------------------------------------------------------------
__global__ __launch_bounds__(256) void v_kernel(
    const float* __restrict__ q_enc, const float* __restrict__ W,
    float* __restrict__ v) {
  const int d  = blockIdx.x * 256 + threadIdx.x;
  const int h0 = blockIdx.y * HC;

  __shared__ float qe[HC][B];
  for (int i = threadIdx.x; i < HC * B; i += 256)
    qe[i >> 5][i & 31] = q_enc[(i & 31) * H + h0 + (i >> 5)];
  __syncthreads();

  float acc[B];
#pragma unroll
  for (int b = 0; b < B; ++b) acc[b] = 0.f;

#pragma unroll 4
  for (int hh = 0; hh < HC; ++hh) {
    const float w = W[(size_t)(h0 + hh) * D + d];
#pragma unroll
    for (int b = 0; b < B; ++b) acc[b] += w * qe[hh][b];
  }
#pragma unroll
  for (int b = 0; b < B; ++b) atomicAdd(&v[b * D + d], acc[b]);
}

// ---------------------------------------------------------------------------
// K5: out[b,p] = dot(v[b], p_sum[b,p]) / len + qb[b], masked. 512 blocks.
// ---------------------------------------------------------------------------
__global__ __launch_bounds__(256) void score_kernel(
    const float* __restrict__ v, const float* __restrict__ p_sum,
    const float* __restrict__ qb, const int* __restrict__ plen,
    float* __restrict__ out) {
  const int bp = blockIdx.x;
  const int b  = bp >> 4;

  const float4* v4 = (const float4*)(v + (size_t)b * D);
  const float4* s4 = (const float4*)(p_sum + (size_t)bp * D);
  float s = 0.f;
#pragma unroll
  for (int k = 0; k < 2; ++k) {
    const int c = k * 256 + threadIdx.x;
    const float4 a = v4[c];
    const float4 x = s4[c];
    s += a.x * x.x + a.y * x.y + a.z * x.z + a.w * x.w;
  }
#pragma unroll
  for (int off = 32; off; off >>= 1) s += __shfl_down(s, off, 64);

  __shared__ float red[4];
  const int lane = threadIdx.x & 63, wid = threadIdx.x >> 6;
  if (lane == 0) red[wid] = s;
  __syncthreads();
  if (threadIdx.x == 0) {
    const int   l   = plen[bp];
    const float tot = red[0] + red[1] + red[2] + red[3];
    const float val = tot / (float)(l > 0 ? l : 1) + qb[b];
    out[bp] = (l > 0) ? val : 0.f;
  }
}

// ---------------------------------------------------------------------------
extern "C" void kernel_launch(void* const* d_in, const int* in_sizes, int n_in,
                              void* d_out, int out_size, void* d_ws, size_t ws_size,
                              hipStream_t stream) {
  const int*   queries = (const int*)d_in[0];
  const int*   qlen    = (const int*)d_in[1];
  const int*   docs    = (const int*)d_in[2];
  const int*   plen    = (const int*)d_in[3];
  const float* emb     = (const float*)d_in[4];
  const float* W       = (const float*)d_in[5];
  const float* bias    = (const float*)d_in[6];
  float*       out     = (float*)d_out;

  float* ws    = (float*)d_ws;
  float* p_sum = ws;                          // B*P*D
  float* v     = p_sum + (size_t)B * P * D;   // B*D
  float* qb    = v + B * D;                   // B
  float* q_rep = qb + B;                      // B*D
  float* q_enc = q_rep + B * D;               // B*H

  zero_kernel<<<(ZERO_N + 255) / 256, 256, 0, stream>>>(ws);
  dim3 pgrid(NC, B);
  psum_kernel<<<pgrid, 256, 0, stream>>>(docs, plen, emb, p_sum);
  qrep_kernel<<<B, 256, 0, stream>>>(queries, qlen, emb, q_rep);
  qenc_kernel<<<H / HB, 256, 0, stream>>>(q_rep, W, bias, q_enc, qb);
  dim3 vgrid(D / 256, H / HC);
  v_kernel<<<vgrid, 256, 0, stream>>>(q_enc, W, v);
  score_kernel<<<B * P, 256, 0, stream>>>(v, p_sum, qb, plen, out);
}

// Round 5
// 776.177 us; speedup vs baseline: 1.0149x; 1.0149x over previous
//
#include <hip/hip_runtime.h>

#define B 32
#define LQ 32
#define DLEN 4096
#define P 16
#define D 2048
#define H 2048
#define NC 64   // doc chunks per batch (grid.x of docseg) -> 2048 blocks
#define HC 32   // h-rows per v_kernel block
#define HB 4    // W-rows per qenc block

// ws layout (floats): v[B*D] | qb[B] | sacc[B*P] | q_rep[B*D] | q_enc[B*H]
#define ZERO_N (B * D + B + B * P)

// ---------------------------------------------------------------------------
// K0: zero v, qb, sacc (contiguous prefix of ws).
// ---------------------------------------------------------------------------
__global__ __launch_bounds__(256) void zero_kernel(float* __restrict__ ws) {
  const int i = blockIdx.x * 256 + threadIdx.x;
  if (i < ZERO_N) ws[i] = 0.f;
}

// ---------------------------------------------------------------------------
// K1: q_rep[b][:] = masked mean of query token embeddings. 32 blocks.
// ---------------------------------------------------------------------------
__global__ __launch_bounds__(256) void qrep_kernel(
    const int* __restrict__ queries, const int* __restrict__ qlen,
    const float* __restrict__ emb, float* __restrict__ q_rep) {
  __shared__ int stok[LQ];
  const int b   = blockIdx.x;
  const int len = qlen[b];
  if (threadIdx.x < len) stok[threadIdx.x] = queries[b * LQ + threadIdx.x];
  __syncthreads();

  float4 a0 = make_float4(0.f, 0.f, 0.f, 0.f);
  float4 a1 = make_float4(0.f, 0.f, 0.f, 0.f);
  for (int t = 0; t < len; ++t) {
    const float4* r = (const float4*)(emb + (size_t)stok[t] * D);
    const float4 x = r[threadIdx.x];
    const float4 y = r[threadIdx.x + 256];
    a0.x += x.x; a0.y += x.y; a0.z += x.z; a0.w += x.w;
    a1.x += y.x; a1.y += y.y; a1.z += y.z; a1.w += y.w;
  }
  const float inv = 1.0f / (float)(len > 0 ? len : 1);
  float4* o = (float4*)(q_rep + (size_t)b * D);
  o[threadIdx.x]       = make_float4(a0.x*inv, a0.y*inv, a0.z*inv, a0.w*inv);
  o[threadIdx.x + 256] = make_float4(a1.x*inv, a1.y*inv, a1.z*inv, a1.w*inv);
}

// ---------------------------------------------------------------------------
// K2: q_enc[b][h] = dot(q_rep[b], W[h]) + bias[h]; accumulates
// qb[b] += q_enc[b][h]*bias[h] (one atomic per block per b).
// ---------------------------------------------------------------------------
__global__ __launch_bounds__(256) void qenc_kernel(
    const float* __restrict__ q_rep, const float* __restrict__ W,
    const float* __restrict__ bias, float* __restrict__ q_enc,
    float* __restrict__ qb) {
  const int h0 = blockIdx.x * HB;
  __shared__ float4 wsh[HB][D / 4];
  for (int i = threadIdx.x; i < HB * (D / 4); i += 256) {
    const int r = i / (D / 4), c = i % (D / 4);
    wsh[r][c] = ((const float4*)(W + (size_t)(h0 + r) * D))[c];
  }
  __syncthreads();

  const int lane = threadIdx.x & 63, wid = threadIdx.x >> 6;
  for (int b = wid; b < B; b += 4) {
    const float4* q4 = (const float4*)(q_rep + (size_t)b * D);
    float s[HB] = {0.f, 0.f, 0.f, 0.f};
#pragma unroll
    for (int j = 0; j < 8; ++j) {
      const float4 q = q4[j * 64 + lane];
#pragma unroll
      for (int r = 0; r < HB; ++r) {
        const float4 w = wsh[r][j * 64 + lane];
        s[r] += w.x * q.x + w.y * q.y + w.z * q.z + w.w * q.w;
      }
    }
    float qbp = 0.f;
#pragma unroll
    for (int r = 0; r < HB; ++r) {
      float t = s[r];
#pragma unroll
      for (int off = 32; off; off >>= 1) t += __shfl_down(t, off, 64);
      if (lane == 0) {
        const float bh  = bias[h0 + r];
        const float val = t + bh;
        q_enc[b * H + h0 + r] = val;
        qbp += val * bh;
      }
    }
    if (lane == 0) atomicAdd(&qb[b], qbp);
  }
}

// ---------------------------------------------------------------------------
// K3: v[b][d] += sum_{h in chunk} q_enc[b][h] * W[h][d]. grid (D/256, H/HC).
// ---------------------------------------------------------------------------
__global__ __launch_bounds__(256) void v_kernel(
    const float* __restrict__ q_enc, const float* __restrict__ W,
    float* __restrict__ v) {
  const int d  = blockIdx.x * 256 + threadIdx.x;
  const int h0 = blockIdx.y * HC;

  __shared__ float qe[HC][B];
  for (int i = threadIdx.x; i < HC * B; i += 256)
    qe[i >> 5][i & 31] = q_enc[(i & 31) * H + h0 + (i >> 5)];
  __syncthreads();

  float acc[B];
#pragma unroll
  for (int b = 0; b < B; ++b) acc[b] = 0.f;

#pragma unroll 4
  for (int hh = 0; hh < HC; ++hh) {
    const float w = W[(size_t)(h0 + hh) * D + d];
#pragma unroll
    for (int b = 0; b < B; ++b) acc[b] += w * qe[hh][b];
  }
#pragma unroll
  for (int b = 0; b < B; ++b) atomicAdd(&v[b * D + d], acc[b]);
}

// ---------------------------------------------------------------------------
// K4 (dominant): fused doc gather + dot. grid = (NC, B).
// Block stages v[b] in LDS and owns a contiguous <=64-token chunk of batch
// b's valid tokens. Chunk spans few passage segments. Per segment: 256
// threads cooperatively stream rows (thread owns 8 fixed columns, fully
// coalesced), accumulate embedding sums in registers (even/odd token
// accumulators for ILP), then ONE dot vs LDS v + wave reduce + 4 atomics.
// ---------------------------------------------------------------------------
__global__ __launch_bounds__(256) void docseg_kernel(
    const int* __restrict__ docs, const int* __restrict__ plen,
    const float* __restrict__ emb, const float* __restrict__ v,
    float* __restrict__ sacc) {
  const int b = blockIdx.y;
  __shared__ float4 vsh[D / 4];   // 8 KB
  __shared__ int    cum[P];
  __shared__ int    stok[64];

  const int tid = threadIdx.x;
  vsh[tid]       = ((const float4*)(v + (size_t)b * D))[tid];
  vsh[tid + 256] = ((const float4*)(v + (size_t)b * D))[tid + 256];
  if (tid == 0) {
    int s = 0;
#pragma unroll
    for (int i = 0; i < P; ++i) { s += plen[b * P + i]; cum[i] = s; }
  }
  __syncthreads();

  const int tot = cum[P - 1];
  const int per = (tot + NC - 1) / NC;             // <= 64
  const int t0  = blockIdx.x * per;
  const int t1  = (t0 + per < tot) ? (t0 + per) : tot;
  if (t0 >= t1) return;
  if (tid < t1 - t0) stok[tid] = docs[b * DLEN + t0 + tid];
  __syncthreads();

  int p = 0;
#pragma unroll
  for (int j = 0; j < P; ++j) p += (cum[j] <= t0) ? 1 : 0;

  const int lane = tid & 63, wid = tid >> 6;
  int segStart = t0;
  while (segStart < t1) {
    const int segEnd = (cum[p] < t1) ? cum[p] : t1;

    float4 e0 = make_float4(0.f,0.f,0.f,0.f), e1 = make_float4(0.f,0.f,0.f,0.f);
    float4 o0 = make_float4(0.f,0.f,0.f,0.f), o1 = make_float4(0.f,0.f,0.f,0.f);
    int t = segStart;
    for (; t + 2 <= segEnd; t += 2) {
      const float4* ra = (const float4*)(emb + (size_t)stok[t - t0] * D);
      const float4* rb = (const float4*)(emb + (size_t)stok[t + 1 - t0] * D);
      const float4 xa = ra[tid], ya = ra[tid + 256];
      const float4 xb = rb[tid], yb = rb[tid + 256];
      e0.x += xa.x; e0.y += xa.y; e0.z += xa.z; e0.w += xa.w;
      e1.x += ya.x; e1.y += ya.y; e1.z += ya.z; e1.w += ya.w;
      o0.x += xb.x; o0.y += xb.y; o0.z += xb.z; o0.w += xb.w;
      o1.x += yb.x; o1.y += yb.y; o1.z += yb.z; o1.w += yb.w;
    }
    if (t < segEnd) {
      const float4* ra = (const float4*)(emb + (size_t)stok[t - t0] * D);
      const float4 xa = ra[tid], ya = ra[tid + 256];
      e0.x += xa.x; e0.y += xa.y; e0.z += xa.z; e0.w += xa.w;
      e1.x += ya.x; e1.y += ya.y; e1.z += ya.z; e1.w += ya.w;
    }

    const float4 va = vsh[tid], vb = vsh[tid + 256];
    float s = (e0.x + o0.x) * va.x + (e0.y + o0.y) * va.y +
              (e0.z + o0.z) * va.z + (e0.w + o0.w) * va.w +
              (e1.x + o1.x) * vb.x + (e1.y + o1.y) * vb.y +
              (e1.z + o1.z) * vb.z + (e1.w + o1.w) * vb.w;
#pragma unroll
    for (int off = 32; off; off >>= 1) s += __shfl_down(s, off, 64);
    if (lane == 0) atomicAdd(&sacc[b * P + p], s);

    segStart = segEnd;
    ++p;
  }
}

// ---------------------------------------------------------------------------
// K5: out[bp] = sacc[bp]/len + qb[b], masked. One 512-thread block.
// ---------------------------------------------------------------------------
__global__ __launch_bounds__(512) void final_kernel(
    const float* __restrict__ sacc, const float* __restrict__ qb,
    const int* __restrict__ plen, float* __restrict__ out) {
  const int i = threadIdx.x;  // 0..511 = b*P+p
  const int l = plen[i];
  const float val = sacc[i] / (float)(l > 0 ? l : 1) + qb[i >> 4];
  out[i] = (l > 0) ? val : 0.f;
}

// ---------------------------------------------------------------------------
extern "C" void kernel_launch(void* const* d_in, const int* in_sizes, int n_in,
                              void* d_out, int out_size, void* d_ws, size_t ws_size,
                              hipStream_t stream) {
  const int*   queries = (const int*)d_in[0];
  const int*   qlen    = (const int*)d_in[1];
  const int*   docs    = (const int*)d_in[2];
  const int*   plen    = (const int*)d_in[3];
  const float* emb     = (const float*)d_in[4];
  const float* W       = (const float*)d_in[5];
  const float* bias    = (const float*)d_in[6];
  float*       out     = (float*)d_out;

  float* ws    = (float*)d_ws;
  float* v     = ws;                 // B*D
  float* qb    = v + B * D;          // B
  float* sacc  = qb + B;             // B*P
  float* q_rep = sacc + B * P;       // B*D
  float* q_enc = q_rep + B * D;      // B*H

  zero_kernel<<<(ZERO_N + 255) / 256, 256, 0, stream>>>(ws);
  qrep_kernel<<<B, 256, 0, stream>>>(queries, qlen, emb, q_rep);
  qenc_kernel<<<H / HB, 256, 0, stream>>>(q_rep, W, bias, q_enc, qb);
  dim3 vgrid(D / 256, H / HC);
  v_kernel<<<vgrid, 256, 0, stream>>>(q_enc, W, v);
  dim3 dgrid(NC, B);
  docseg_kernel<<<dgrid, 256, 0, stream>>>(docs, plen, emb, v, sacc);
  final_kernel<<<1, 512, 0, stream>>>(sacc, qb, plen, out);
}